// Round 1
// baseline (174.569 us; speedup 1.0000x reference)
//
#include <hip/hip_runtime.h>
#include <cstdint>
#include <cstddef>

typedef __bf16 bf16x8 __attribute__((ext_vector_type(8)));
typedef float f32x4 __attribute__((ext_vector_type(4)));
typedef unsigned int u32x4 __attribute__((ext_vector_type(4)));

#define MFMA16(a, b, c) __builtin_amdgcn_mfma_f32_16x16x32_bf16((a), (b), (c), 0, 0, 0)

static constexpr int CD = 128;
static constexpr int NTOK = 65536;
static constexpr float F_SCALE = 0.17677669529663688f;  // 1/sqrt(32)
static constexpr float F_LOG2E = 1.4426950408889634f;
static constexpr int K1_CB = 128;      // k1 blocks per batch
static constexpr int PART = 4224;      // 4096 S + 128 Z floats per partial

__device__ __forceinline__ void gload_lds16(const float* g, void* l) {
  __builtin_amdgcn_global_load_lds(
      (const __attribute__((address_space(1))) void*)g,
      (__attribute__((address_space(3))) void*)l, 16, 0, 0);
}

// Stage [128][64] fp32 tile (rows c, cols n) from src into T1 (linear row-major,
// 256B row stride). Each wave stages its 32 rows with 8 global_load_lds dwordx4.
__device__ __forceinline__ void stage_tile(const float* src_base, int n0,
                                           float* T1, int w, int lg, int l15) {
#pragma unroll
  for (int i = 0; i < 8; ++i) {
    int c = w * 32 + i * 4;
    const float* gp = src_base + (size_t)(c + lg) * NTOK + n0 + l15 * 4;
    gload_lds16(gp, (void*)(T1 + c * 64));
  }
}

// Transpose T1 [128c][64n] fp32 -> T2 [64n][128c] bf16, XOR-swizzled (16B granule).
__device__ __forceinline__ void transpose_tile(const float* T1, char* T2, int tid) {
  int nl = tid & 63;
  int xk = (nl & 7) << 4;
#pragma unroll
  for (int u = 0; u < 4; ++u) {
    int co = (tid >> 6) * 4 + u;  // c-octet index 0..15
    u32x4 pk;
#pragma unroll
    for (int jj = 0; jj < 4; ++jj) {
      float f0 = T1[(co * 8 + 2 * jj) * 64 + nl];
      float f1 = T1[(co * 8 + 2 * jj + 1) * 64 + nl];
      unsigned short u0 = __builtin_bit_cast(unsigned short, (__bf16)f0);
      unsigned short u1 = __builtin_bit_cast(unsigned short, (__bf16)f1);
      pk[jj] = (unsigned int)u0 | ((unsigned int)u1 << 16);
    }
    *(u32x4*)(T2 + nl * 256 + ((co * 16) ^ xk)) = pk;
  }
}

// ---------------- kernel 1: context -> S,Z partials ----------------
// grid 512 = 4 batches x 128 chunks, 256 threads. Each block: 512 cols = 8 strips.
__global__ __launch_bounds__(256, 2) void k1_ctx(
    const float* __restrict__ ctx_in, const float* __restrict__ Wk,
    const float* __restrict__ Wv, float* __restrict__ S_part) {
  __shared__ char smem[48 * 1024];
  float* T1 = (float*)smem;            // [128][64] f32 (aliased later by E/V)
  char* T2 = smem + 32 * 1024;         // [64][128] bf16 swizzled
  char* EV = smem;                     // per-wave E/V regions alias T1

  const int tid = threadIdx.x;
  const int lane = tid & 63;
  const int w = tid >> 6;
  const int l15 = lane & 15;
  const int lg = lane >> 4;
  const int b = blockIdx.x >> 7;
  const int cb = blockIdx.x & 127;

  // Weight A-fragments in registers. m=0,1 -> Wk rows (prescaled by log2e); m=2,3 -> Wv.
  bf16x8 Af[4][4];
#pragma unroll
  for (int m = 0; m < 4; ++m) {
    const float* Wp = (m < 2) ? Wk : Wv;
    const float sc = (m < 2) ? F_LOG2E : 1.0f;
    int row = w * 32 + (m & 1) * 16 + l15;
#pragma unroll
    for (int s = 0; s < 4; ++s) {
      const float* p = Wp + row * CD + s * 32 + lg * 8;
#pragma unroll
      for (int e = 0; e < 8; ++e) Af[m][s][e] = (__bf16)(p[e] * sc);
    }
  }

  f32x4 Sacc[2][2];
#pragma unroll
  for (int i = 0; i < 2; ++i)
#pragma unroll
    for (int j = 0; j < 2; ++j) Sacc[i][j] = f32x4{0.f, 0.f, 0.f, 0.f};
  float zpart[2][4] = {{0.f, 0.f, 0.f, 0.f}, {0.f, 0.f, 0.f, 0.f}};

  const float* src_base = ctx_in + (size_t)b * CD * NTOK + cb * 512;
  const int xorr = (lane & 7) << 4;
  char* Ew = EV + w * 8192;
  char* Vw = EV + w * 8192 + 4096;

  for (int strip = 0; strip < 8; ++strip) {
    const int n0 = strip * 64;
    stage_tile(src_base, n0, T1, w, lg, l15);
    asm volatile("s_waitcnt vmcnt(0)" ::: "memory");
    __syncthreads();
    transpose_tile(T1, T2, tid);
    __syncthreads();

    // projection MFMAs: D[row=weight row][col=n], 64 cols
    f32x4 acc[4][4];
#pragma unroll
    for (int m = 0; m < 4; ++m)
#pragma unroll
      for (int t = 0; t < 4; ++t) acc[m][t] = f32x4{0.f, 0.f, 0.f, 0.f};
#pragma unroll
    for (int s = 0; s < 4; ++s) {
      bf16x8 Bf[4];
#pragma unroll
      for (int t = 0; t < 4; ++t) {
        int n = t * 16 + l15;
        Bf[t] = *(const bf16x8*)(T2 + n * 256 + ((s * 64 + lg * 16) ^ xorr));
      }
#pragma unroll
      for (int m = 0; m < 4; ++m)
#pragma unroll
        for (int t = 0; t < 4; ++t) acc[m][t] = MFMA16(Af[m][s], Bf[t], acc[m][t]);
    }

    // exp (exp2 of prescaled) + Z partials + E/V bf16 tiles in wave-local LDS
#pragma unroll
    for (int m = 0; m < 2; ++m)
#pragma unroll
      for (int t = 0; t < 4; ++t)
#pragma unroll
        for (int r = 0; r < 4; ++r) {
          float ev = __builtin_exp2f(acc[m][t][r]);
          zpart[m][r] += ev;
          int d = m * 16 + lg * 4 + r;
          int n = t * 16 + l15;
          *(__bf16*)(Ew + d * 128 + ((2 * n) ^ ((d & 7) << 4))) = (__bf16)ev;
          int e2 = d;  // same local row index for V rows
          *(__bf16*)(Vw + e2 * 128 + ((2 * n) ^ ((e2 & 7) << 4))) = (__bf16)acc[m + 2][t][r];
        }

    // S-MFMA: S[d][e] += E[d][n] * V[e][n], K = 64 (this strip)
#pragma unroll
    for (int s2 = 0; s2 < 2; ++s2) {
      bf16x8 Ea[2], Vb[2];
#pragma unroll
      for (int md = 0; md < 2; ++md) {
        int d = md * 16 + l15;
        Ea[md] = *(const bf16x8*)(Ew + d * 128 + ((s2 * 64 + lg * 16) ^ ((d & 7) << 4)));
        int e2 = md * 16 + l15;
        Vb[md] = *(const bf16x8*)(Vw + e2 * 128 + ((s2 * 64 + lg * 16) ^ ((e2 & 7) << 4)));
      }
#pragma unroll
      for (int md = 0; md < 2; ++md)
#pragma unroll
        for (int ne = 0; ne < 2; ++ne) Sacc[md][ne] = MFMA16(Ea[md], Vb[ne], Sacc[md][ne]);
    }
    __syncthreads();
  }

  // write partials: S then Z (deterministic, per-block slot)
  float* outp = S_part + (size_t)(b * K1_CB + cb) * PART;
#pragma unroll
  for (int md = 0; md < 2; ++md)
#pragma unroll
    for (int ne = 0; ne < 2; ++ne)
#pragma unroll
      for (int r = 0; r < 4; ++r) {
        int d = md * 16 + lg * 4 + r;
        int e = ne * 16 + l15;
        outp[w * 1024 + d * 32 + e] = Sacc[md][ne][r];
      }
#pragma unroll
  for (int m = 0; m < 2; ++m)
#pragma unroll
    for (int r = 0; r < 4; ++r) {
      float z = zpart[m][r];
      z += __shfl_xor(z, 1, 16);
      z += __shfl_xor(z, 2, 16);
      z += __shfl_xor(z, 4, 16);
      z += __shfl_xor(z, 8, 16);
      if (l15 == 0) {
        int d = m * 16 + lg * 4 + r;
        outp[4096 + w * 32 + d] = z;
      }
    }
}

// ---------------- kernel 2a: reduce partials ----------------
// grid 4*33: bs<32 reduce 128 S elems, bs==32 reduce 128 Z elems.
__global__ void k2a_reduce(const float* __restrict__ S_part, float* __restrict__ S_red,
                           float* __restrict__ Z_red) {
  int bid = blockIdx.x;
  int b = bid / 33, bs = bid % 33;
  int tid = threadIdx.x;
  __shared__ float red[256];
  int e_loc = tid & 127, half = tid >> 7;
  const float* base = S_part + (size_t)b * K1_CB * PART + (bs < 32 ? bs * 128 + e_loc : 4096 + e_loc);
  float sum = 0.f;
  for (int p = half * 64; p < half * 64 + 64; ++p) sum += base[(size_t)p * PART];
  red[tid] = sum;
  __syncthreads();
  if (tid < 128) {
    float v = red[tid] + red[tid + 128];
    if (bs < 32)
      S_red[b * 4096 + bs * 128 + tid] = v;
    else
      Z_red[b * 128 + tid] = v;
  }
}

// ---------------- kernel 2b: ctx = S/Z; T = Wo*ctx; W_eff = SCALE*T*Wq ----------------
// grid 32 = 4 batches x 8 o-groups of 16 rows.
__global__ void k2b_weff(const float* __restrict__ S_red, const float* __restrict__ Z_red,
                         const float* __restrict__ Wq, const float* __restrict__ Wo,
                         float* __restrict__ W_eff) {
  int b = blockIdx.x >> 3, og = blockIdx.x & 7;
  int tid = threadIdx.x;
  __shared__ float ctx_lds[4096];
  __shared__ float T_lds[16 * 128];
  for (int i = tid * 16; i < tid * 16 + 16; ++i)
    ctx_lds[i] = S_red[b * 4096 + i] / Z_red[b * 128 + (i >> 5)];
  __syncthreads();
  {
    int o_loc = tid >> 4, hd0 = (tid & 15) * 8;
    int o = og * 16 + o_loc;
    for (int j = 0; j < 8; ++j) {
      int hd = hd0 + j, h = hd >> 5, d = hd & 31;
      const float* wo = Wo + o * 128 + h * 32;
      const float* cx = ctx_lds + h * 1024 + d * 32;
      float acc = 0.f;
      for (int e = 0; e < 32; ++e) acc += wo[e] * cx[e];
      T_lds[o_loc * 128 + hd] = acc;
    }
  }
  __syncthreads();
  {
    int o_loc = tid >> 4, c0 = (tid & 15) * 8;
    float acc[8] = {};
    const float* Trow = T_lds + o_loc * 128;
    for (int hd = 0; hd < 128; ++hd) {
      float tv = Trow[hd];
      const float* wq = Wq + hd * 128 + c0;
#pragma unroll
      for (int j = 0; j < 8; ++j) acc[j] += tv * wq[j];
    }
    float* op = W_eff + b * 16384 + (og * 16 + o_loc) * 128 + c0;
#pragma unroll
    for (int j = 0; j < 8; ++j) op[j] = F_SCALE * acc[j];
  }
}

// ---------------- kernel 3: out = W_eff[b] @ x[b] + bo ----------------
// grid 1024 = 4 batches x 256 chunks of 256 cols (4 strips of 64).
__global__ __launch_bounds__(256, 2) void k3_out(const float* __restrict__ x,
                                                 const float* __restrict__ W_eff,
                                                 const float* __restrict__ bo,
                                                 float* __restrict__ out) {
  __shared__ char smem[48 * 1024];
  float* T1 = (float*)smem;
  char* T2 = smem + 32 * 1024;
  const int tid = threadIdx.x;
  const int lane = tid & 63;
  const int w = tid >> 6;
  const int l15 = lane & 15;
  const int lg = lane >> 4;
  const int b = blockIdx.x >> 8;
  const int cb = blockIdx.x & 255;

  bf16x8 Af[2][4];
#pragma unroll
  for (int m = 0; m < 2; ++m) {
    int o = w * 32 + m * 16 + l15;
#pragma unroll
    for (int s = 0; s < 4; ++s) {
      const float* p = W_eff + b * 16384 + o * 128 + s * 32 + lg * 8;
#pragma unroll
      for (int e = 0; e < 8; ++e) Af[m][s][e] = (__bf16)p[e];
    }
  }
  float bof[2][4];
#pragma unroll
  for (int m = 0; m < 2; ++m)
#pragma unroll
    for (int r = 0; r < 4; ++r) bof[m][r] = bo[w * 32 + m * 16 + lg * 4 + r];

  const float* src_base = x + (size_t)b * CD * NTOK + cb * 256;
  float* out_base = out + (size_t)b * CD * NTOK + cb * 256;
  const int xorr = (lane & 7) << 4;

  for (int strip = 0; strip < 4; ++strip) {
    const int n0 = strip * 64;
    stage_tile(src_base, n0, T1, w, lg, l15);
    asm volatile("s_waitcnt vmcnt(0)" ::: "memory");
    __syncthreads();
    transpose_tile(T1, T2, tid);
    __syncthreads();

    f32x4 acc[2][4];
#pragma unroll
    for (int m = 0; m < 2; ++m)
#pragma unroll
      for (int t = 0; t < 4; ++t) acc[m][t] = f32x4{0.f, 0.f, 0.f, 0.f};
#pragma unroll
    for (int s = 0; s < 4; ++s) {
      bf16x8 Bf[4];
#pragma unroll
      for (int t = 0; t < 4; ++t) {
        int n = t * 16 + l15;
        Bf[t] = *(const bf16x8*)(T2 + n * 256 + ((s * 64 + lg * 16) ^ xorr));
      }
#pragma unroll
      for (int m = 0; m < 2; ++m)
#pragma unroll
        for (int t = 0; t < 4; ++t) acc[m][t] = MFMA16(Af[m][s], Bf[t], acc[m][t]);
    }
#pragma unroll
    for (int m = 0; m < 2; ++m)
#pragma unroll
      for (int t = 0; t < 4; ++t)
#pragma unroll
        for (int r = 0; r < 4; ++r) {
          int o = w * 32 + m * 16 + lg * 4 + r;
          out_base[(size_t)o * NTOK + n0 + t * 16 + l15] = acc[m][t][r] + bof[m][r];
        }
    __syncthreads();
  }
}

extern "C" void kernel_launch(void* const* d_in, const int* in_sizes, int n_in,
                              void* d_out, int out_size, void* d_ws, size_t ws_size,
                              hipStream_t stream) {
  const float* x = (const float*)d_in[0];
  const float* ctxg = (const float*)d_in[1];
  const float* Wq = (const float*)d_in[2];
  const float* Wk = (const float*)d_in[3];
  const float* Wv = (const float*)d_in[4];
  const float* Wo = (const float*)d_in[5];
  const float* bo = (const float*)d_in[6];
  float* out = (float*)d_out;

  float* ws = (float*)d_ws;
  float* S_part = ws;                        // 512*4224 floats
  float* S_red = ws + 512 * PART;            // 16384
  float* Z_red = S_red + 16384;              // 512
  float* W_eff = Z_red + 512;                // 65536

  k1_ctx<<<dim3(512), dim3(256), 0, stream>>>(ctxg, Wk, Wv, S_part);
  k2a_reduce<<<dim3(132), dim3(256), 0, stream>>>(S_part, S_red, Z_red);
  k2b_weff<<<dim3(32), dim3(256), 0, stream>>>(S_red, Z_red, Wq, Wo, W_eff);
  k3_out<<<dim3(1024), dim3(256), 0, stream>>>(x, W_eff, bo, out);
}

// Round 2
// 164.946 us; speedup vs baseline: 1.0583x; 1.0583x over previous
//
#include <hip/hip_runtime.h>
#include <cstdint>
#include <cstddef>

typedef __bf16 bf16x8 __attribute__((ext_vector_type(8)));
typedef float f32x4 __attribute__((ext_vector_type(4)));
typedef unsigned int u32x4 __attribute__((ext_vector_type(4)));
typedef unsigned int u32x2 __attribute__((ext_vector_type(2)));

#define MFMA16(a, b, c) __builtin_amdgcn_mfma_f32_16x16x32_bf16((a), (b), (c), 0, 0, 0)

static constexpr int CD = 128;
static constexpr int NTOK = 65536;
static constexpr float F_SCALE = 0.17677669529663688f;  // 1/sqrt(32)
static constexpr float F_LOG2E = 1.4426950408889634f;
static constexpr int PART = 4224;  // 4096 S + 128 Z floats per block partial

__device__ __forceinline__ void gload_lds16(const float* g, void* l) {
  __builtin_amdgcn_global_load_lds(
      (const __attribute__((address_space(1))) void*)g,
      (__attribute__((address_space(3))) void*)l, 16, 0, 0);
}

__device__ __forceinline__ unsigned short bfb(float f) {
  return __builtin_bit_cast(unsigned short, (__bf16)f);
}
__device__ __forceinline__ unsigned pk2(float a, float b) {
  return (unsigned)bfb(a) | ((unsigned)bfb(b) << 16);
}

// Stage a [128 c][64 n] fp32 strip into T1 with granule pre-swizzle on the
// GLOBAL address: stored granule g holds logical granule g ^ ((row>>3)&3).
// LDS dest is linear (global_load_lds: base + lane*16B). Wave w stages rows
// [32w, 32w+32) -- the same rows it later transposes.
__device__ __forceinline__ void stage_swz(const float* src_base, float* T1,
                                          int w, int lg, int l15) {
#pragma unroll
  for (int i = 0; i < 8; ++i) {
    int c0 = w * 32 + i * 4;
    int row = c0 + lg;
    int g = l15 ^ ((row >> 3) & 3);
    gload_lds16(src_base + (size_t)row * NTOK + g * 4, (void*)(T1 + c0 * 64));
  }
}

// Transpose T1 [128 c][64 n] fp32 (granule-swizzled) -> T2 [64 n][128 c] bf16,
// XOR-swizzled rows. 8 ds_read_b128 + 4 ds_write_b128 per thread, both
// conflict-free (8 bank-classes x 8 lanes).
__device__ __forceinline__ void transpose_vec(const float* T1, char* T2, int tid) {
  const int co = tid >> 4;   // c-octet 0..15
  const int nq = tid & 15;   // n-quad  0..15
  const int lgl = co & 3;    // == (c>>3)&3 for all rows this thread reads
  f32x4 M[8];
#pragma unroll
  for (int i = 0; i < 8; ++i)
    M[i] = *(const f32x4*)(T1 + (co * 8 + i) * 64 + ((nq ^ lgl) * 4));
#pragma unroll
  for (int j = 0; j < 4; ++j) {
    int n = nq * 4 + j;
    u32x4 pk;
#pragma unroll
    for (int p = 0; p < 4; ++p)
      pk[p] = pk2(M[2 * p][j], M[2 * p + 1][j]);
    *(u32x4*)(T2 + n * 256 + ((co * 16) ^ ((n & 7) << 4))) = pk;
  }
}

// ---------------- kernel 1: context -> S,Z partials ----------------
// grid = 4 batches x (1<<cpb_log2) chunks; each chunk = nstrips strips of 64 cols.
// Operand-swapped MFMA: A = data (row=n), B = weights (col=weight row).
__global__ __launch_bounds__(256, 2) void k1_ctx(
    const float* __restrict__ ctx_in, const float* __restrict__ Wk,
    const float* __restrict__ Wv, float* __restrict__ S_part,
    int cpb_log2, int nstrips) {
  __shared__ char smem[80 * 1024];
  float* T1 = (float*)smem;        // 32KB fp32 strip
  char* T2 = smem + 32 * 1024;     // 16KB bf16 transposed
  char* EV = smem + 48 * 1024;     // 32KB: 8KB per wave (E 4KB + V 4KB)

  const int tid = threadIdx.x;
  const int lane = tid & 63;
  const int w = tid >> 6;
  const int l15 = lane & 15;
  const int lg = lane >> 4;
  const int b = blockIdx.x >> cpb_log2;
  const int cb = blockIdx.x & ((1 << cpb_log2) - 1);

  // Weight B-fragments: col = weight row = base + l15, k = c = ks*32 + lg*8.
  // m=0,1 -> Wk rows (prescaled by log2e); m=2,3 -> Wv rows. Wave w = head w.
  bf16x8 Wf[4][4];
#pragma unroll
  for (int m = 0; m < 4; ++m) {
    const float* Wp = (m < 2) ? Wk : Wv;
    const float sc = (m < 2) ? F_LOG2E : 1.0f;
    int row = w * 32 + (m & 1) * 16 + l15;
#pragma unroll
    for (int ks = 0; ks < 4; ++ks) {
      const float* p = Wp + row * CD + ks * 32 + lg * 8;
#pragma unroll
      for (int e = 0; e < 8; ++e) Wf[m][ks][e] = (__bf16)(p[e] * sc);
    }
  }

  f32x4 Sacc[2][2];
#pragma unroll
  for (int i = 0; i < 2; ++i)
#pragma unroll
    for (int j = 0; j < 2; ++j) Sacc[i][j] = f32x4{0.f, 0.f, 0.f, 0.f};
  float zacc[2] = {0.f, 0.f};

  const float* src0 = ctx_in + (size_t)b * CD * NTOK + (size_t)cb * (nstrips * 64);
  const int xorr = (l15 & 7) << 4;
  char* Ew = EV + w * 8192;
  char* Vw = EV + w * 8192 + 4096;

  stage_swz(src0, T1, w, lg, l15);

  for (int s = 0; s < nstrips; ++s) {
    asm volatile("s_waitcnt vmcnt(0)" ::: "memory");
    __syncthreads();  // DMA landed; prev compute's T2 reads done
    transpose_vec(T1, T2, tid);
    __syncthreads();  // T2 visible; T1 free
    if (s + 1 < nstrips) stage_swz(src0 + (s + 1) * 64, T1, w, lg, l15);  // overlaps compute

    // projections: D[n][weight-row]
    f32x4 acc[4][4];
#pragma unroll
    for (int m = 0; m < 4; ++m)
#pragma unroll
      for (int t = 0; t < 4; ++t) acc[m][t] = f32x4{0.f, 0.f, 0.f, 0.f};
#pragma unroll
    for (int ks = 0; ks < 4; ++ks) {
      bf16x8 At[4];
#pragma unroll
      for (int t = 0; t < 4; ++t) {
        int n = t * 16 + l15;
        At[t] = *(const bf16x8*)(T2 + n * 256 + ((ks * 64 + lg * 16) ^ xorr));
      }
#pragma unroll
      for (int m = 0; m < 4; ++m)
#pragma unroll
        for (int t = 0; t < 4; ++t) acc[m][t] = MFMA16(At[t], Wf[m][ks], acc[m][t]);
    }

    // exp (exp2 of prescaled) + packed E/V writes ([d][n] bf16, XOR-swizzled).
    // Thread's 4 acc values are 4 consecutive n at fixed d -> one b64 write.
#pragma unroll
    for (int m = 0; m < 2; ++m) {
      int d = m * 16 + l15;
      int dx = (d & 7) << 4;
#pragma unroll
      for (int t = 0; t < 4; ++t) {
        f32x4 a = acc[m][t];
        float e0 = __builtin_exp2f(a[0]), e1 = __builtin_exp2f(a[1]);
        float e2 = __builtin_exp2f(a[2]), e3 = __builtin_exp2f(a[3]);
        zacc[m] += (e0 + e1) + (e2 + e3);
        u32x2 pe{pk2(e0, e1), pk2(e2, e3)};
        *(u32x2*)(Ew + d * 128 + ((t * 32 + lg * 8) ^ dx)) = pe;
        f32x4 v = acc[m + 2][t];
        u32x2 pv{pk2(v[0], v[1]), pk2(v[2], v[3])};
        *(u32x2*)(Vw + d * 128 + ((t * 32 + lg * 8) ^ dx)) = pv;
      }
    }

    // S-MFMA: S[d][e] += E[d][n] * V[e][n], K = 64 (wave-private, no barrier)
#pragma unroll
    for (int s2 = 0; s2 < 2; ++s2) {
      bf16x8 Ea[2], Vb[2];
#pragma unroll
      for (int md = 0; md < 2; ++md) {
        int d = md * 16 + l15;
        int off = (s2 * 64 + lg * 16) ^ ((d & 7) << 4);
        Ea[md] = *(const bf16x8*)(Ew + d * 128 + off);
        Vb[md] = *(const bf16x8*)(Vw + d * 128 + off);
      }
#pragma unroll
      for (int md = 0; md < 2; ++md)
#pragma unroll
        for (int ne = 0; ne < 2; ++ne) Sacc[md][ne] = MFMA16(Ea[md], Vb[ne], Sacc[md][ne]);
    }
  }

  // Partials, stored [e][d] so the f32x4 (4 consecutive d) packs: flat = e*32+d.
  float* outp = S_part + (size_t)blockIdx.x * PART;
#pragma unroll
  for (int md = 0; md < 2; ++md)
#pragma unroll
    for (int ne = 0; ne < 2; ++ne) {
      int e = ne * 16 + l15, d0 = md * 16 + lg * 4;
      *(f32x4*)(outp + w * 1024 + e * 32 + d0) = Sacc[md][ne];
    }
#pragma unroll
  for (int m = 0; m < 2; ++m) {
    float z = zacc[m];
    z += __shfl_xor(z, 16, 64);
    z += __shfl_xor(z, 32, 64);
    if (lg == 0) outp[4096 + w * 32 + m * 16 + l15] = z;
  }
}

// ---------------- kernel 2a: reduce partials ----------------
__global__ void k2a_reduce(const float* __restrict__ S_part, float* __restrict__ S_red,
                           float* __restrict__ Z_red, int nparts) {
  int bid = blockIdx.x;
  int b = bid / 33, bs = bid % 33;
  int tid = threadIdx.x;
  __shared__ float red[256];
  int e_loc = tid & 127, half = tid >> 7;
  const float* base =
      S_part + (size_t)b * nparts * PART + (bs < 32 ? bs * 128 + e_loc : 4096 + e_loc);
  float sum = 0.f;
  int h = nparts >> 1;
  for (int p = half * h; p < half * h + h; ++p) sum += base[(size_t)p * PART];
  red[tid] = sum;
  __syncthreads();
  if (tid < 128) {
    float v = red[tid] + red[tid + 128];
    if (bs < 32)
      S_red[b * 4096 + bs * 128 + tid] = v;
    else
      Z_red[b * 128 + tid] = v;
  }
}

// ---------------- kernel 2b: ctx = S/Z; T = Wo*ctx; W_eff = SCALE*T*Wq ----------------
// S layout is [h][e][d] (flat h*1024 + e*32 + d), ctx[h][d][e] = S/Z[h][d].
__global__ void k2b_weff(const float* __restrict__ S_red, const float* __restrict__ Z_red,
                         const float* __restrict__ Wq, const float* __restrict__ Wo,
                         float* __restrict__ W_eff) {
  int b = blockIdx.x >> 3, og = blockIdx.x & 7;
  int tid = threadIdx.x;
  __shared__ float ctx_lds[4096];
  __shared__ float T_lds[16 * 128];
  for (int i = tid * 16; i < tid * 16 + 16; ++i) {
    int hh = i >> 10, dd = i & 31;
    ctx_lds[i] = S_red[b * 4096 + i] / Z_red[b * 128 + hh * 32 + dd];
  }
  __syncthreads();
  {
    int o_loc = tid >> 4, hd0 = (tid & 15) * 8;
    int o = og * 16 + o_loc;
    for (int j = 0; j < 8; ++j) {
      int hd = hd0 + j, h = hd >> 5, d = hd & 31;
      const float* wo = Wo + o * 128 + h * 32;
      const float* cx = ctx_lds + h * 1024 + d;  // stride 32 over e
      float acc = 0.f;
      for (int e = 0; e < 32; ++e) acc += wo[e] * cx[e * 32];
      T_lds[o_loc * 128 + hd] = acc;
    }
  }
  __syncthreads();
  {
    int o_loc = tid >> 4, c0 = (tid & 15) * 8;
    float acc[8] = {};
    const float* Trow = T_lds + o_loc * 128;
    for (int hd = 0; hd < 128; ++hd) {
      float tv = Trow[hd];
      const float* wq = Wq + hd * 128 + c0;
#pragma unroll
      for (int j = 0; j < 8; ++j) acc[j] += tv * wq[j];
    }
    float* op = W_eff + b * 16384 + (og * 16 + o_loc) * 128 + c0;
#pragma unroll
    for (int j = 0; j < 8; ++j) op[j] = F_SCALE * acc[j];
  }
}

// ---------------- kernel 3: out = W_eff[b] @ x[b] + bo ----------------
// grid 1024 = 4 batches x 256 chunks of 256 cols (4 strips). Operand-swapped:
// D[n][o] -> thread's 4 values = 4 consecutive n -> global_store_dwordx4.
__global__ __launch_bounds__(256, 3) void k3_out(const float* __restrict__ x,
                                                 const float* __restrict__ W_eff,
                                                 const float* __restrict__ bo,
                                                 float* __restrict__ out) {
  __shared__ char smem[48 * 1024];
  float* T1 = (float*)smem;
  char* T2 = smem + 32 * 1024;
  const int tid = threadIdx.x;
  const int lane = tid & 63;
  const int w = tid >> 6;
  const int l15 = lane & 15;
  const int lg = lane >> 4;
  const int b = blockIdx.x >> 8;
  const int cb = blockIdx.x & 255;

  bf16x8 Wf[2][4];
#pragma unroll
  for (int m = 0; m < 2; ++m) {
    int o = w * 32 + m * 16 + l15;
#pragma unroll
    for (int ks = 0; ks < 4; ++ks) {
      const float* p = W_eff + b * 16384 + o * 128 + ks * 32 + lg * 8;
#pragma unroll
      for (int e = 0; e < 8; ++e) Wf[m][ks][e] = (__bf16)p[e];
    }
  }
  float bof[2] = {bo[w * 32 + l15], bo[w * 32 + 16 + l15]};

  const float* src0 = x + (size_t)b * CD * NTOK + cb * 256;
  float* out0 = out + (size_t)b * CD * NTOK + cb * 256;
  const int xorr = (l15 & 7) << 4;

  stage_swz(src0, T1, w, lg, l15);

  for (int s = 0; s < 4; ++s) {
    asm volatile("s_waitcnt vmcnt(0)" ::: "memory");
    __syncthreads();
    transpose_vec(T1, T2, tid);
    __syncthreads();
    if (s + 1 < 4) stage_swz(src0 + (s + 1) * 64, T1, w, lg, l15);

    f32x4 acc[2][4];
#pragma unroll
    for (int m = 0; m < 2; ++m)
#pragma unroll
      for (int t = 0; t < 4; ++t) acc[m][t] = f32x4{0.f, 0.f, 0.f, 0.f};
#pragma unroll
    for (int ks = 0; ks < 4; ++ks) {
      bf16x8 At[4];
#pragma unroll
      for (int t = 0; t < 4; ++t) {
        int n = t * 16 + l15;
        At[t] = *(const bf16x8*)(T2 + n * 256 + ((ks * 64 + lg * 16) ^ xorr));
      }
#pragma unroll
      for (int m = 0; m < 2; ++m)
#pragma unroll
        for (int t = 0; t < 4; ++t) acc[m][t] = MFMA16(At[t], Wf[m][ks], acc[m][t]);
    }
#pragma unroll
    for (int m = 0; m < 2; ++m) {
      int o = w * 32 + m * 16 + l15;
#pragma unroll
      for (int t = 0; t < 4; ++t) {
        f32x4 v = acc[m][t];
        v[0] += bof[m]; v[1] += bof[m]; v[2] += bof[m]; v[3] += bof[m];
        *(f32x4*)(out0 + (size_t)o * NTOK + s * 64 + t * 16 + lg * 4) = v;
      }
    }
  }
}

extern "C" void kernel_launch(void* const* d_in, const int* in_sizes, int n_in,
                              void* d_out, int out_size, void* d_ws, size_t ws_size,
                              hipStream_t stream) {
  const float* x = (const float*)d_in[0];
  const float* ctxg = (const float*)d_in[1];
  const float* Wq = (const float*)d_in[2];
  const float* Wk = (const float*)d_in[3];
  const float* Wv = (const float*)d_in[4];
  const float* Wo = (const float*)d_in[5];
  const float* bo = (const float*)d_in[6];
  float* out = (float*)d_out;

  // Prefer 1024 k1 blocks (256 cols each) if ws fits the partial buffer.
  size_t need256 = ((size_t)1024 * PART + 16384 + 512 + 65536) * sizeof(float);
  int cpb_log2, nstrips;
  if (ws_size >= need256) { cpb_log2 = 8; nstrips = 4; }
  else                    { cpb_log2 = 7; nstrips = 8; }
  int nblk1 = 4 << cpb_log2;

  float* ws = (float*)d_ws;
  float* S_part = ws;
  float* S_red = ws + (size_t)nblk1 * PART;
  float* Z_red = S_red + 16384;
  float* W_eff = Z_red + 512;

  k1_ctx<<<dim3(nblk1), dim3(256), 0, stream>>>(ctxg, Wk, Wv, S_part, cpb_log2, nstrips);
  k2a_reduce<<<dim3(132), dim3(256), 0, stream>>>(S_part, S_red, Z_red, 1 << cpb_log2);
  k2b_weff<<<dim3(32), dim3(256), 0, stream>>>(S_red, Z_red, Wq, Wo, W_eff);
  k3_out<<<dim3(1024), dim3(256), 0, stream>>>(x, W_eff, bo, out);
}